// Round 5
// baseline (515.976 us; speedup 1.0000x reference)
//
#include <hip/hip_runtime.h>
#include <hip/hip_bf16.h>

// GLIFR forward, MI355X.
//   S_ff(T,B,H) bf16 = x @ W_iv                   (GEMM 128x128, 1600 blocks)
//   for chunk c in 0..9 (20 steps == DELAY):
//     if c>0: P[0..3] = F[c-1] @ W_lat  (split-K=4 partials, 640 blocks 128x128)
//     k_rec: syn = S_ff + sum(P); ASC/volt/firing x20 -> F bf16
//   out(B,T,O) f32 = F @ w_out + b_out            (GEMM 128x128, 400 blocks)
// GEMM: 128x128 tile, BK=64, dbuf LDS + early-issue global_load_lds w16,
// XOR-chunk swizzle (0 conflicts), bijective XCD swizzle, split-K via
// separate bf16 partial buffers (no atomics).

#define B_ 64
#define T_ 200
#define I_ 512
#define H_ 2048
#define O_ 512
#define BH_ 131072
#define DELAY_ 20
#define DT_ 0.05f
#define RMEM_ 0.1f

typedef __bf16 bf16x8 __attribute__((ext_vector_type(8)));
typedef float f32x4 __attribute__((ext_vector_type(4)));

__device__ __forceinline__ unsigned short f2bf(float f) {
    unsigned int u = __builtin_bit_cast(unsigned int, f);
    u = (u + 0x7fff + ((u >> 16) & 1)) >> 16;
    return (unsigned short)u;
}
__device__ __forceinline__ float bf2f(unsigned short u) {
    return __builtin_bit_cast(float, (unsigned int)u << 16);
}

__device__ __forceinline__ void gload16(const void* g, void* l) {
    __builtin_amdgcn_global_load_lds(
        (const __attribute__((address_space(1))) unsigned int*)g,
        (__attribute__((address_space(3))) unsigned int*)l, 16, 0, 0);
}

// ---------- f32 -> bf16 (same layout) ----------
__global__ void k_cvt4(const float* __restrict__ in, unsigned short* __restrict__ out, int n4) {
    int i = blockIdx.x * 256 + threadIdx.x;
    if (i >= n4) return;
    float4 v = ((const float4*)in)[i];
    ushort4 o;
    o.x = f2bf(v.x); o.y = f2bf(v.y); o.z = f2bf(v.z); o.w = f2bf(v.w);
    ((ushort4*)out)[i] = o;
}

// ---------- f32 (R x C) -> bf16 transposed (C x R), 32x32 LDS tiles ----------
__global__ __launch_bounds__(256) void k_tcvt(const float* __restrict__ in,
                                              unsigned short* __restrict__ out, int R, int C) {
    __shared__ float t[32][33];
    int bx = blockIdx.x, by = blockIdx.y;
    int tx = threadIdx.x & 31, ty = threadIdx.x >> 5;
    #pragma unroll
    for (int r = 0; r < 32; r += 8)
        t[ty + r][tx] = in[(size_t)(by * 32 + ty + r) * C + bx * 32 + tx];
    __syncthreads();
    #pragma unroll
    for (int r = 0; r < 32; r += 8)
        out[(size_t)(bx * 32 + ty + r) * R + by * 32 + tx] = f2bf(t[tx][ty + r]);
}

// ---------- bf16 GEMM 128x128: C = A(M x kfull) * Bt(N x kfull)^T ----------
// amap/cmap==1: m -> (m&63)*200 + (m>>6). ksplit: block computes K-slice
// [split*klen, (split+1)*klen) and writes C + split*csplit (bf16 partials).
// cbf16: store bf16, else f32 (+bias).
__global__ __launch_bounds__(256) void k_gemm(
    const unsigned short* __restrict__ A, const unsigned short* __restrict__ Bt,
    void* __restrict__ Cv, const float* __restrict__ bias,
    int kfull, int lda, int ldb, int ldc, int amap, int cmap, int cbf16,
    int ksplit, long long csplit, int gx, int gy)
{
    __shared__ unsigned short As[2 * 128 * 64];
    __shared__ unsigned short Bs[2 * 128 * 64];

    const int nb = gx * gy * ksplit;
    const int hw = blockIdx.x;
    const int wid = (hw & 7) * (nb >> 3) + (hw >> 3);
    const int layer = gx * gy;
    const int split = wid / layer;
    const int w2 = wid % layer;
    int bm, bn;
    if (gx <= gy) { bn = w2 % gx; bm = w2 / gx; }
    else          { bm = w2 % gy; bn = w2 / gy; }

    const int klen = kfull / ksplit;
    const int kbase = split * klen;

    const int tid = threadIdx.x;
    const int lane = tid & 63, wave = tid >> 6;
    const int wr = (wave >> 1) * 64, wc = (wave & 1) * 64;
    const int fr = lane & 15, kg = lane >> 4;
    const int rx = fr & 7;

    // staging: slot s = (row, cp); global chunk cg = cp ^ (row&7)
    const unsigned short* Ap[4]; const unsigned short* Bp[4]; int ls[4];
    #pragma unroll
    for (int it = 0; it < 4; ++it) {
        int s = tid + it * 256;
        int row = s >> 3, cp = s & 7, cg = cp ^ (row & 7);
        int gm = bm * 128 + row;
        int ar = amap ? ((gm & 63) * 200 + (gm >> 6)) : gm;
        Ap[it] = A + (size_t)ar * lda + kbase + cg * 8;
        Bp[it] = Bt + (size_t)(bn * 128 + row) * ldb + kbase + cg * 8;
        ls[it] = s * 8;
    }

    auto stage = [&](int buf, int kt) {
        const int ko = kt * 64;
        #pragma unroll
        for (int it = 0; it < 4; ++it) {
            gload16(Ap[it] + ko, &As[buf * 128 * 64 + ls[it]]);
            gload16(Bp[it] + ko, &Bs[buf * 128 * 64 + ls[it]]);
        }
    };

    f32x4 acc[4][4] = {};
    const int nk = klen >> 6;

    stage(0, 0);
    __syncthreads();
    for (int kt = 0; kt < nk; ++kt) {
        const int cur = kt & 1;
        if (kt + 1 < nk) stage(cur ^ 1, kt + 1);   // issue next-tile loads first
        #pragma unroll
        for (int kk = 0; kk < 2; ++kk) {
            const int ck = (kk << 2) | kg;
            bf16x8 af[4], bfr[4];
            #pragma unroll
            for (int i = 0; i < 4; ++i) {
                af[i]  = *(const bf16x8*)(&As[cur * 8192 + (wr + i * 16 + fr) * 64 + ((ck ^ rx) << 3)]);
                bfr[i] = *(const bf16x8*)(&Bs[cur * 8192 + (wc + i * 16 + fr) * 64 + ((ck ^ rx) << 3)]);
            }
            #pragma unroll
            for (int i = 0; i < 4; ++i)
                #pragma unroll
                for (int j = 0; j < 4; ++j)
                    acc[i][j] = __builtin_amdgcn_mfma_f32_16x16x32_bf16(af[i], bfr[j], acc[i][j], 0, 0, 0);
        }
        __syncthreads();
    }

    unsigned short* Cb = (unsigned short*)Cv + (size_t)split * csplit;
    float*          Cf = (float*)Cv;
    #pragma unroll
    for (int i = 0; i < 4; ++i) {
        int rbase = bm * 128 + wr + i * 16 + kg * 4;
        #pragma unroll
        for (int j = 0; j < 4; ++j) {
            int col = bn * 128 + wc + j * 16 + fr;
            #pragma unroll
            for (int r = 0; r < 4; ++r) {
                int m = rbase + r;
                int cr = cmap ? ((m & 63) * 200 + (m >> 6)) : m;
                float v = acc[i][j][r];
                if (cbf16) {
                    Cb[(size_t)cr * ldc + col] = f2bf(v);
                } else {
                    if (bias) v += bias[col];
                    Cf[(size_t)cr * ldc + col] = v;
                }
            }
        }
    }
}

// ---------- per-(b,h) recurrence over one chunk; syn = S_ff + sum partials ----
__global__ __launch_bounds__(256) void k_rec(
    const unsigned short* __restrict__ Sff, const unsigned short* __restrict__ P,
    int nparts, unsigned short* __restrict__ F,
    float* __restrict__ volt, float* __restrict__ fire, float* __restrict__ asc,
    const float* __restrict__ thresh, const float* __restrict__ km,
    const float* __restrict__ asc_amp, const float* __restrict__ asc_r,
    const float* __restrict__ asc_k, int t0)
{
    int idx = blockIdx.x * 256 + threadIdx.x;
    int h = idx & (H_ - 1);
    float v = volt[idx], f = fire[idx];
    float a0 = asc[idx], a1 = asc[BH_ + idx];
    float th = thresh[h], k = km[h];
    float amp0 = asc_amp[h], amp1 = asc_amp[H_ + h];
    float r0 = asc_r[h], r1 = asc_r[H_ + h];
    float d0 = expf(-DT_ * asc_k[h]), d1 = expf(-DT_ * asc_k[H_ + h]);
    const float dtk = DT_ * k;
    for (int t = 0; t < DELAY_; ++t) {
        float syn = bf2f(Sff[(size_t)(t0 + t) * BH_ + idx]);
        if (nparts) {
            size_t po = (size_t)t * BH_ + idx;
            syn += bf2f(P[po]) + bf2f(P[(size_t)DELAY_ * BH_ + po])
                 + bf2f(P[2 * (size_t)DELAY_ * BH_ + po]) + bf2f(P[3 * (size_t)DELAY_ * BH_ + po]);
        }
        float na0 = a0 * d0 + f * (r0 * a0 + amp0);
        float na1 = a1 * d1 + f * (r1 * a1 + amp1);
        a0 = na0; a1 = na1;
        float tot = syn + a0 + a1;
        v = v * (1.f - f);
        v = v + dtk * (RMEM_ * tot - v);
        f = 1.f / (1.f + expf(-(v - th)));
        F[(size_t)(t0 + t) * BH_ + idx] = f2bf(f);
    }
    volt[idx] = v; fire[idx] = f;
    asc[idx] = a0; asc[BH_ + idx] = a1;
}

extern "C" void kernel_launch(void* const* d_in, const int* in_sizes, int n_in,
                              void* d_out, int out_size, void* d_ws, size_t ws_size,
                              hipStream_t stream) {
    const float* x       = (const float*)d_in[0];
    const float* w_iv    = (const float*)d_in[1];
    const float* w_lat   = (const float*)d_in[2];
    const float* thresh  = (const float*)d_in[3];
    const float* km      = (const float*)d_in[4];
    const float* asc_amp = (const float*)d_in[5];
    const float* asc_r   = (const float*)d_in[6];
    const float* asc_k   = (const float*)d_in[7];
    const float* w_out   = (const float*)d_in[8];
    const float* b_out   = (const float*)d_in[9];
    float* out = (float*)d_out;

    char* ws = (char*)d_ws;
    unsigned short* Sff   = (unsigned short*)ws;                          // 52,428,800 (T,B,H) bf16
    unsigned short* Fb    = (unsigned short*)(ws + 52428800);             // 52,428,800 (T,B,H) bf16
    unsigned short* xb    = (unsigned short*)(ws + 104857600);            // 13,107,200
    unsigned short* WivT  = (unsigned short*)(ws + 117964800);            //  2,097,152 (H,I)
    unsigned short* WlatT = (unsigned short*)(ws + 120061952);            //  8,388,608 (H,H)
    unsigned short* WoutT = (unsigned short*)(ws + 128450560);            //  2,097,152 (O,H)
    unsigned short* P     = (unsigned short*)(ws + 130547712);            // 20,971,520 (4,DELAY,B,H)
    float*          volt  = (float*)(ws + 151519232);
    float*          fire  = (float*)(ws + 152043520);
    float*          asc   = (float*)(ws + 152567808);                     // 2*BH f32

    k_cvt4<<<6400, 256, 0, stream>>>(x, xb, (B_ * T_ * I_) / 4);
    k_tcvt<<<dim3(H_ / 32, I_ / 32), 256, 0, stream>>>(w_iv, WivT, I_, H_);
    k_tcvt<<<dim3(H_ / 32, H_ / 32), 256, 0, stream>>>(w_lat, WlatT, H_, H_);
    k_tcvt<<<dim3(O_ / 32, H_ / 32), 256, 0, stream>>>(w_out, WoutT, H_, O_);

    hipMemsetAsync(volt, 0, 524288 + 524288 + 1048576, stream);

    // S_ff = x @ W_iv : 100x16 = 1600 blocks, bf16 out
    k_gemm<<<(B_ * T_ / 128) * (H_ / 128), 256, 0, stream>>>(
        xb, WivT, Sff, nullptr, I_, I_, I_, H_, 1, 0, 1, 1, 0, H_ / 128, B_ * T_ / 128);

    for (int c = 0; c < T_ / DELAY_; ++c) {
        if (c) {
            // P[s] = F[c-1] @ W_lat (K-slice s) : 4 x (10x16) = 640 blocks
            k_gemm<<<(DELAY_ * B_ / 128) * (H_ / 128) * 4, 256, 0, stream>>>(
                Fb + (size_t)(c - 1) * DELAY_ * BH_, WlatT, P, nullptr,
                H_, H_, H_, H_, 0, 0, 1, 4, (long long)DELAY_ * BH_,
                H_ / 128, DELAY_ * B_ / 128);
        }
        k_rec<<<BH_ / 256, 256, 0, stream>>>(Sff, P, c ? 4 : 0, Fb, volt, fire, asc,
                                             thresh, km, asc_amp, asc_r, asc_k,
                                             c * DELAY_);
    }

    // out = F @ w_out + b_out : 100x4 = 400 blocks, f32 out, cmap (t,b)->(b,t)
    k_gemm<<<(B_ * T_ / 128) * (O_ / 128), 256, 0, stream>>>(
        Fb, WoutT, out, b_out, H_, H_, H_, O_, 0, 1, 0, 1, 0, O_ / 128, B_ * T_ / 128);
}